// Round 2
// baseline (31281.644 us; speedup 1.0000x reference)
//
#include <hip/hip_runtime.h>
#include <math.h>

#define HD 1024
#define SEQ 512
#define VOCAB 32000
#define NCHUNK 8000
#define SCAN_WGS 256   // one wave per WG, one WG per CU

// ---------------- init: LSE state + scan flags ----------------
__global__ __launch_bounds__(512) void init_state(float* m, float* s, float* tl, unsigned* flags) {
    int tid = threadIdx.x;
    m[tid] = -INFINITY;
    s[tid] = 0.f;
    tl[tid] = 0.f;
    for (int i = tid; i < 3 * SCAN_WGS; i += 512) flags[i] = 0u;
}

// ---------------- embedding gather: out[t][:] = emb[idx[t]][:] ----------------
__global__ __launch_bounds__(256) void gather_rows(const float* __restrict__ emb,
                                                   const int* __restrict__ idx,
                                                   float* __restrict__ out, int ncols) {
    int t = blockIdx.x;
    int src = idx[t];
    const float4* sp = (const float4*)(emb + (size_t)src * ncols);
    float4* dp = (float4*)(out + (size_t)t * ncols);
    for (int i = threadIdx.x; i < ncols / 4; i += blockDim.x) dp[i] = sp[i];
}

// ---------------- copy Hp into right half of CH ----------------
__global__ __launch_bounds__(256) void copy_right(const float* __restrict__ Hp, float* __restrict__ CH) {
    int t = blockIdx.x;
    const float4* sp = (const float4*)(Hp + (size_t)t * HD);
    float4* dp = (float4*)(CH + (size_t)t * (2 * HD) + HD);
    for (int i = threadIdx.x; i < HD / 4; i += blockDim.x) dp[i] = sp[i];
}

// ---------------- transpose: in[R][C] -> out[C][R] ----------------
__global__ __launch_bounds__(256) void transpose_k(const float* __restrict__ in, float* __restrict__ out,
                                                   int R, int C) {
    __shared__ float tile[32][33];
    int c0 = blockIdx.x * 32, r0 = blockIdx.y * 32;
    int tx = threadIdx.x, ty = threadIdx.y;  // block (32,8)
    for (int i = ty; i < 32; i += 8)
        tile[i][tx] = in[(size_t)(r0 + i) * C + c0 + tx];
    __syncthreads();
    for (int i = ty; i < 32; i += 8)
        out[(size_t)(c0 + i) * R + r0 + tx] = tile[tx][i];
}

// ---------------- fp32 GEMM: C[M,N] = act(A[M,K] @ B[N,K]^T + bias[N]) ----------------
// row-major, BM=BN=64, BK=16, 256 threads, 4x4 micro-tile, ldc param.
__global__ __launch_bounds__(256) void gemm_nt(const float* __restrict__ A, const float* __restrict__ B,
                                               const float* __restrict__ bias, float* __restrict__ C,
                                               int M, int N, int K, int ldc, int act) {
    __shared__ float As[16][68];
    __shared__ float Bs[16][68];
    const int tid = threadIdx.x;
    const int row0 = blockIdx.y * 64, col0 = blockIdx.x * 64;
    const int tx = tid & 15, ty = tid >> 4;
    const int lr = tid >> 2, lk = (tid & 3) << 2;
    const float* Ap = A + (size_t)(row0 + lr) * K + lk;
    const float* Bp = B + (size_t)(col0 + lr) * K + lk;
    float acc[4][4] = {};
    for (int k0 = 0; k0 < K; k0 += 16) {
        float4 a = *(const float4*)(Ap + k0);
        float4 b = *(const float4*)(Bp + k0);
        As[lk + 0][lr] = a.x; As[lk + 1][lr] = a.y; As[lk + 2][lr] = a.z; As[lk + 3][lr] = a.w;
        Bs[lk + 0][lr] = b.x; Bs[lk + 1][lr] = b.y; Bs[lk + 2][lr] = b.z; Bs[lk + 3][lr] = b.w;
        __syncthreads();
#pragma unroll
        for (int kk = 0; kk < 16; ++kk) {
            const float4 av = *(const float4*)&As[kk][ty * 4];
            const float4 bv = *(const float4*)&Bs[kk][tx * 4];
            const float a0[4] = {av.x, av.y, av.z, av.w};
            const float b0[4] = {bv.x, bv.y, bv.z, bv.w};
#pragma unroll
            for (int i = 0; i < 4; ++i)
#pragma unroll
                for (int j = 0; j < 4; ++j) acc[i][j] += a0[i] * b0[j];
        }
        __syncthreads();
    }
#pragma unroll
    for (int i = 0; i < 4; ++i) {
        float4 v;
        float* vp = &v.x;
#pragma unroll
        for (int j = 0; j < 4; ++j) {
            float x = acc[i][j];
            if (bias) x += bias[col0 + tx * 4 + j];
            if (act) x = tanhf(x);
            vp[j] = x;
        }
        *(float4*)(C + (size_t)(row0 + ty * 4 + i) * ldc + col0 + tx * 4) = v;
    }
}

// ---------------- persistent RNN scan, register-resident weights ----------------
// h_t = tanh(X[t] + Wh @ h_{t-1}); Wh[i][j] multiplies h[j] (i.e. h @ Wh^T).
// 256 WGs x 64 threads (one wave each). WG wid owns output rows [4*wid, 4*wid+4).
// Lane l holds Wh[row][16l..16l+16) in VGPRs (64 VGPRs of weights, loaded once).
// Step t publishes h_t into Hout row (out0+t) via agent-scope atomic stores, then
// release-stores flags[wid]=t+1. All waves poll the 256 flags (lane l checks
// flags[4l..4l+4)) and re-load h with agent-scope atomic loads (cross-XCD safe;
// monotone addresses -> no stale-line reuse).
// write_h0: Hout[0]=h0, steps write rows 1..T; else steps write rows 0..T-1.
__global__ __launch_bounds__(64) void scan_rnn2(const float* __restrict__ X,
                                                const float* __restrict__ Wh,
                                                const float* __restrict__ h0,
                                                float* __restrict__ Hout,
                                                unsigned* __restrict__ flags,
                                                int T, int write_h0) {
    const int wid = blockIdx.x;   // 0..255
    const int lane = threadIdx.x; // 0..63
    const int row0 = wid * 4;
    // ---- preload weights into VGPRs ----
    float4 w[4][4];
#pragma unroll
    for (int r = 0; r < 4; ++r) {
        const float* wp = Wh + (size_t)(row0 + r) * HD + lane * 16;
#pragma unroll
        for (int c = 0; c < 4; ++c) w[r][c] = *(const float4*)(wp + c * 4);
    }
    const int out0 = write_h0 ? 1 : 0;
    if (write_h0 && lane == 0)
        *(float4*)(Hout + row0) = *(const float4*)(h0 + row0);
    // ---- initial h (plain loads: h0 written before this kernel) ----
    float h[16];
#pragma unroll
    for (int c = 0; c < 16; ++c) h[c] = h0[lane * 16 + c];

    for (int t = 0; t < T; ++t) {
        // x for this step's 4 rows (only lane 0 consumes it)
        float4 xv;
        if (lane == 0) xv = *(const float4*)(X + (size_t)t * HD + row0);
        // ---- 4 row partial dots (16 MACs each) ----
        float acc[4];
#pragma unroll
        for (int r = 0; r < 4; ++r) {
            float a = 0.f;
#pragma unroll
            for (int c = 0; c < 4; ++c) {
                const float4 wv = w[r][c];
                a += wv.x * h[c * 4 + 0] + wv.y * h[c * 4 + 1] +
                     wv.z * h[c * 4 + 2] + wv.w * h[c * 4 + 3];
            }
            acc[r] = a;
        }
        // ---- wave reduction (64 lanes) ----
#pragma unroll
        for (int r = 0; r < 4; ++r) {
#pragma unroll
            for (int off = 32; off; off >>= 1) acc[r] += __shfl_down(acc[r], off);
        }
        // ---- publish h_t ----
        if (lane == 0) {
            float o0 = tanhf(xv.x + acc[0]);
            float o1 = tanhf(xv.y + acc[1]);
            float o2 = tanhf(xv.z + acc[2]);
            float o3 = tanhf(xv.w + acc[3]);
            float* orow = Hout + (size_t)(out0 + t) * HD + row0;
            __hip_atomic_store(&orow[0], o0, __ATOMIC_RELAXED, __HIP_MEMORY_SCOPE_AGENT);
            __hip_atomic_store(&orow[1], o1, __ATOMIC_RELAXED, __HIP_MEMORY_SCOPE_AGENT);
            __hip_atomic_store(&orow[2], o2, __ATOMIC_RELAXED, __HIP_MEMORY_SCOPE_AGENT);
            __hip_atomic_store(&orow[3], o3, __ATOMIC_RELAXED, __HIP_MEMORY_SCOPE_AGENT);
            __hip_atomic_store(&flags[wid], (unsigned)(t + 1),
                               __ATOMIC_RELEASE, __HIP_MEMORY_SCOPE_AGENT);
        }
        if (t + 1 < T) {
            // ---- wait for all 256 producers of step t ----
            const unsigned want = (unsigned)(t + 1);
            const unsigned* fb = flags + lane * 4;
            int ok;
            do {
                unsigned f0 = __hip_atomic_load(&fb[0], __ATOMIC_ACQUIRE, __HIP_MEMORY_SCOPE_AGENT);
                unsigned f1 = __hip_atomic_load(&fb[1], __ATOMIC_ACQUIRE, __HIP_MEMORY_SCOPE_AGENT);
                unsigned f2 = __hip_atomic_load(&fb[2], __ATOMIC_ACQUIRE, __HIP_MEMORY_SCOPE_AGENT);
                unsigned f3 = __hip_atomic_load(&fb[3], __ATOMIC_ACQUIRE, __HIP_MEMORY_SCOPE_AGENT);
                ok = (f0 >= want) & (f1 >= want) & (f2 >= want) & (f3 >= want);
            } while (!__all(ok));
            // ---- reload h_t (agent-scope: written by other XCDs) ----
            const float* hrow = Hout + (size_t)(out0 + t) * HD + lane * 16;
#pragma unroll
            for (int c = 0; c < 16; ++c)
                h[c] = __hip_atomic_load(&hrow[c], __ATOMIC_RELAXED, __HIP_MEMORY_SCOPE_AGENT);
        }
    }
}

// ---------------- row softmax in place ----------------
__global__ __launch_bounds__(256) void softmax_rows(float* __restrict__ S, int N) {
    __shared__ float red[256];
    const int row = blockIdx.x, tid = threadIdx.x;
    float* r = S + (size_t)row * N;
    float lm = -INFINITY;
    for (int i = tid; i < N; i += 256) lm = fmaxf(lm, r[i]);
    red[tid] = lm; __syncthreads();
    for (int o = 128; o; o >>= 1) { if (tid < o) red[tid] = fmaxf(red[tid], red[tid + o]); __syncthreads(); }
    const float M = red[0]; __syncthreads();
    float ls = 0.f;
    for (int i = tid; i < N; i += 256) { float e = expf(r[i] - M); r[i] = e; ls += e; }
    red[tid] = ls; __syncthreads();
    for (int o = 128; o; o >>= 1) { if (tid < o) red[tid] += red[tid + o]; __syncthreads(); }
    const float inv = 1.f / red[0];
    for (int i = tid; i < N; i += 256) r[i] *= inv;
}

// ---------------- online logsumexp over a logits chunk ----------------
__global__ __launch_bounds__(256) void lse_chunk(const float* __restrict__ L, int CN, int c0,
                                                 const int* __restrict__ tgt, float* __restrict__ m,
                                                 float* __restrict__ s, float* __restrict__ tl) {
    __shared__ float red[256];
    const int row = blockIdx.x, tid = threadIdx.x;
    const float* lr = L + (size_t)row * CN;
    float lm = -INFINITY;
    for (int i = tid; i < CN; i += 256) lm = fmaxf(lm, lr[i]);
    red[tid] = lm; __syncthreads();
    for (int o = 128; o; o >>= 1) { if (tid < o) red[tid] = fmaxf(red[tid], red[tid + o]); __syncthreads(); }
    const float M = red[0]; __syncthreads();
    float ls = 0.f;
    for (int i = tid; i < CN; i += 256) ls += expf(lr[i] - M);
    red[tid] = ls; __syncthreads();
    for (int o = 128; o; o >>= 1) { if (tid < o) red[tid] += red[tid + o]; __syncthreads(); }
    if (tid == 0) {
        const float S = red[0];
        const float m0 = m[row];
        const float nm = fmaxf(m0, M);
        const float s0 = s[row];
        const float ns = (m0 == -INFINITY ? 0.f : s0 * expf(m0 - nm)) + S * expf(M - nm);
        m[row] = nm; s[row] = ns;
        const int tg = tgt[row] - c0;
        if (tg >= 0 && tg < CN) tl[row] = lr[tg];
    }
}

// ---------------- final: sum_t (m + log s - tgt_logit) ----------------
__global__ __launch_bounds__(512) void final_loss(const float* __restrict__ m, const float* __restrict__ s,
                                                  const float* __restrict__ tl, float* __restrict__ out) {
    __shared__ float red[512];
    const int tid = threadIdx.x;
    red[tid] = m[tid] + logf(s[tid]) - tl[tid];
    __syncthreads();
    for (int o = 256; o; o >>= 1) { if (tid < o) red[tid] += red[tid + o]; __syncthreads(); }
    if (tid == 0) out[0] = red[0];
}

extern "C" void kernel_launch(void* const* d_in, const int* in_sizes, int n_in,
                              void* d_out, int out_size, void* d_ws, size_t ws_size,
                              hipStream_t stream) {
    const int* src_nums  = (const int*)d_in[0];
    const int* tgt_nums  = (const int*)d_in[1];
    const float* src_emb = (const float*)d_in[2];
    const float* Wx1     = (const float*)d_in[3];
    const float* Wh1     = (const float*)d_in[4];
    const float* b1      = (const float*)d_in[5];
    const float* h01     = (const float*)d_in[6];
    const float* Wx2     = (const float*)d_in[7];
    const float* Wh2     = (const float*)d_in[8];
    const float* b2      = (const float*)d_in[9];
    const float* h02     = (const float*)d_in[10];
    const float* tgt_emb = (const float*)d_in[11];
    const float* dh0     = (const float*)d_in[12];
    const float* dWx     = (const float*)d_in[13];
    const float* dWh     = (const float*)d_in[14];
    const float* db      = (const float*)d_in[15];
    const float* tnhW    = (const float*)d_in[16];
    const float* tnhb    = (const float*)d_in[17];
    const float* outW    = (const float*)d_in[18];
    const float* outb    = (const float*)d_in[19];
    float* out = (float*)d_out;

    float* ws = (float*)d_ws;
    size_t off = 0;
    auto alloc = [&](size_t n) { float* p = ws + off; off += n; return p; };
    float* E     = alloc((size_t)SEQ * HD);
    float* X     = alloc((size_t)SEQ * HD);
    float* H1    = alloc((size_t)SEQ * HD);
    float* Henc  = alloc((size_t)SEQ * HD);
    float* Hp    = alloc((size_t)SEQ * HD);
    float* HencT = alloc((size_t)HD * SEQ);
    float* Satt  = alloc((size_t)SEQ * SEQ);
    float* CH    = alloc((size_t)SEQ * 2 * HD);
    float* Z     = alloc((size_t)SEQ * HD);
    float* Lc    = alloc((size_t)SEQ * NCHUNK);
    float* mrow  = alloc(SEQ);
    float* srow  = alloc(SEQ);
    float* tlrow = alloc(SEQ);
    unsigned* flags = (unsigned*)(ws + off); off += 3 * SCAN_WGS;

    init_state<<<1, 512, 0, stream>>>(mrow, srow, tlrow, flags);

    // ---- encoder ----
    gather_rows<<<SEQ, 256, 0, stream>>>(src_emb, src_nums, E, HD);
    gemm_nt<<<dim3(HD / 64, SEQ / 64), 256, 0, stream>>>(E, Wx1, b1, X, SEQ, HD, HD, HD, 0);
    scan_rnn2<<<SCAN_WGS, 64, 0, stream>>>(X, Wh1, h01, H1, flags + 0 * SCAN_WGS, SEQ, 0);
    gemm_nt<<<dim3(HD / 64, SEQ / 64), 256, 0, stream>>>(H1, Wx2, b2, X, SEQ, HD, HD, HD, 0);
    scan_rnn2<<<SCAN_WGS, 64, 0, stream>>>(X, Wh2, h02, Henc, flags + 1 * SCAN_WGS, SEQ, 0);

    // ---- decoder hidden-state scan (pre-step states Hp[0..511]) ----
    gather_rows<<<SEQ, 256, 0, stream>>>(tgt_emb, tgt_nums, E, HD);
    gemm_nt<<<dim3(HD / 64, SEQ / 64), 256, 0, stream>>>(E, dWx, db, X, SEQ, HD, HD, HD, 0);
    scan_rnn2<<<SCAN_WGS, 64, 0, stream>>>(X, dWh, dh0, Hp, flags + 2 * SCAN_WGS, SEQ - 1, 1);

    // ---- batched attention ----
    gemm_nt<<<dim3(SEQ / 64, SEQ / 64), 256, 0, stream>>>(Hp, Henc, nullptr, Satt, SEQ, SEQ, HD, SEQ, 0);
    softmax_rows<<<SEQ, 256, 0, stream>>>(Satt, SEQ);
    transpose_k<<<dim3(HD / 32, SEQ / 32), dim3(32, 8), 0, stream>>>(Henc, HencT, SEQ, HD);
    gemm_nt<<<dim3(HD / 64, SEQ / 64), 256, 0, stream>>>(Satt, HencT, nullptr, CH, SEQ, HD, SEQ, 2 * HD, 0);
    copy_right<<<SEQ, 256, 0, stream>>>(Hp, CH);
    gemm_nt<<<dim3(HD / 64, SEQ / 64), 256, 0, stream>>>(CH, tnhW, tnhb, Z, SEQ, HD, 2 * HD, HD, 1);

    // ---- logits + online logsumexp, chunked over vocab ----
    for (int c = 0; c < VOCAB / NCHUNK; ++c) {
        gemm_nt<<<dim3(NCHUNK / 64, SEQ / 64), 256, 0, stream>>>(
            Z, outW + (size_t)c * NCHUNK * HD, outb + (size_t)c * NCHUNK, Lc, SEQ, NCHUNK, HD, NCHUNK, 0);
        lse_chunk<<<SEQ, 256, 0, stream>>>(Lc, NCHUNK, c * NCHUNK, tgt_nums, mrow, srow, tlrow);
    }
    final_loss<<<1, 512, 0, stream>>>(mrow, srow, tlrow, out);
}

// Round 3
// 6362.912 us; speedup vs baseline: 4.9162x; 4.9162x over previous
//
#include <hip/hip_runtime.h>
#include <math.h>

#define HD 1024
#define SEQ 512
#define VOCAB 32000
#define NCHUNK 8000
#define SCAN_WGS 256   // one wave per WG, ~one WG per CU
#define SENT 0xAAAAAAAAu

// ---------------- init: LSE state ----------------
__global__ __launch_bounds__(512) void init_state(float* m, float* s, float* tl) {
    int tid = threadIdx.x;
    m[tid] = -INFINITY;
    s[tid] = 0.f;
    tl[tid] = 0.f;
}

// ---------------- sentinel fill for scan output buffers ----------------
__global__ __launch_bounds__(256) void fill_sentinel(float4* p, int n4) {
    const float s = __uint_as_float(SENT);
    const float4 v = {s, s, s, s};
    int i = blockIdx.x * 256 + threadIdx.x;
    int stride = gridDim.x * 256;
    for (; i < n4; i += stride) p[i] = v;
}

// ---------------- embedding gather: out[t][:] = emb[idx[t]][:] ----------------
__global__ __launch_bounds__(256) void gather_rows(const float* __restrict__ emb,
                                                   const int* __restrict__ idx,
                                                   float* __restrict__ out, int ncols) {
    int t = blockIdx.x;
    int src = idx[t];
    const float4* sp = (const float4*)(emb + (size_t)src * ncols);
    float4* dp = (float4*)(out + (size_t)t * ncols);
    for (int i = threadIdx.x; i < ncols / 4; i += blockDim.x) dp[i] = sp[i];
}

// ---------------- copy Hp into right half of CH ----------------
__global__ __launch_bounds__(256) void copy_right(const float* __restrict__ Hp, float* __restrict__ CH) {
    int t = blockIdx.x;
    const float4* sp = (const float4*)(Hp + (size_t)t * HD);
    float4* dp = (float4*)(CH + (size_t)t * (2 * HD) + HD);
    for (int i = threadIdx.x; i < HD / 4; i += blockDim.x) dp[i] = sp[i];
}

// ---------------- transpose: in[R][C] -> out[C][R] ----------------
__global__ __launch_bounds__(256) void transpose_k(const float* __restrict__ in, float* __restrict__ out,
                                                   int R, int C) {
    __shared__ float tile[32][33];
    int c0 = blockIdx.x * 32, r0 = blockIdx.y * 32;
    int tx = threadIdx.x, ty = threadIdx.y;  // block (32,8)
    for (int i = ty; i < 32; i += 8)
        tile[i][tx] = in[(size_t)(r0 + i) * C + c0 + tx];
    __syncthreads();
    for (int i = ty; i < 32; i += 8)
        out[(size_t)(c0 + i) * R + r0 + tx] = tile[tx][i];
}

// ---------------- fp32 GEMM: C[M,N] = act(A[M,K] @ B[N,K]^T + bias[N]) ----------------
__global__ __launch_bounds__(256) void gemm_nt(const float* __restrict__ A, const float* __restrict__ B,
                                               const float* __restrict__ bias, float* __restrict__ C,
                                               int M, int N, int K, int ldc, int act) {
    __shared__ float As[16][68];
    __shared__ float Bs[16][68];
    const int tid = threadIdx.x;
    const int row0 = blockIdx.y * 64, col0 = blockIdx.x * 64;
    const int tx = tid & 15, ty = tid >> 4;
    const int lr = tid >> 2, lk = (tid & 3) << 2;
    const float* Ap = A + (size_t)(row0 + lr) * K + lk;
    const float* Bp = B + (size_t)(col0 + lr) * K + lk;
    float acc[4][4] = {};
    for (int k0 = 0; k0 < K; k0 += 16) {
        float4 a = *(const float4*)(Ap + k0);
        float4 b = *(const float4*)(Bp + k0);
        As[lk + 0][lr] = a.x; As[lk + 1][lr] = a.y; As[lk + 2][lr] = a.z; As[lk + 3][lr] = a.w;
        Bs[lk + 0][lr] = b.x; Bs[lk + 1][lr] = b.y; Bs[lk + 2][lr] = b.z; Bs[lk + 3][lr] = b.w;
        __syncthreads();
#pragma unroll
        for (int kk = 0; kk < 16; ++kk) {
            const float4 av = *(const float4*)&As[kk][ty * 4];
            const float4 bv = *(const float4*)&Bs[kk][tx * 4];
            const float a0[4] = {av.x, av.y, av.z, av.w};
            const float b0[4] = {bv.x, bv.y, bv.z, bv.w};
#pragma unroll
            for (int i = 0; i < 4; ++i)
#pragma unroll
                for (int j = 0; j < 4; ++j) acc[i][j] += a0[i] * b0[j];
        }
        __syncthreads();
    }
#pragma unroll
    for (int i = 0; i < 4; ++i) {
        float4 v;
        float* vp = &v.x;
#pragma unroll
        for (int j = 0; j < 4; ++j) {
            float x = acc[i][j];
            if (bias) x += bias[col0 + tx * 4 + j];
            if (act) x = tanhf(x);
            vp[j] = x;
        }
        *(float4*)(C + (size_t)(row0 + ty * 4 + i) * ldc + col0 + tx * 4) = v;
    }
}

// ---------------- persistent RNN scan, register weights, sentinel-poll sync ----------------
// h_t = tanh(X[t] + Wh @ h_{t-1}).  256 WGs x 64 threads; WG wid owns rows [4wid,4wid+4).
// Lane l holds Wh[row][16l..16l+16) in VGPRs.  All cross-WG traffic uses RELAXED
// agent-scope atomics (plain sc1 loads/stores straight to coherent L3 — NO buffer_inv /
// buffer_wbl2 cache maintenance, which made acquire/release polling cost 19.6 us/step).
// Sync is data-carried: Hout rows are pre-filled with SENT; a dword is valid when its
// bit pattern != SENT (tanh output colliding with SENT has P~1e-14; collision => hang,
// not wrong answer).  Consumers poll their own 16-dword slice of row t — the poll IS
// the data load, so no fences are needed at all.
// write_h0: Hout[0]=h0 (plain store, never polled), steps write rows 1..T.
__global__ __launch_bounds__(64) void scan_rnn3(const float* __restrict__ X,
                                                const float* __restrict__ Wh,
                                                const float* __restrict__ h0,
                                                float* __restrict__ Hout,
                                                int T, int write_h0) {
    const int wid = blockIdx.x;   // 0..255
    const int lane = threadIdx.x; // 0..63
    const int row0 = wid * 4;
    // ---- preload weights into VGPRs (64 VGPRs) ----
    float4 w[4][4];
#pragma unroll
    for (int r = 0; r < 4; ++r) {
        const float* wp = Wh + (size_t)(row0 + r) * HD + lane * 16;
#pragma unroll
        for (int c = 0; c < 4; ++c) w[r][c] = *(const float4*)(wp + c * 4);
    }
    const int out0 = write_h0 ? 1 : 0;
    if (write_h0 && lane < 4) Hout[row0 + lane] = h0[row0 + lane];
    float h[16];
#pragma unroll
    for (int c = 0; c < 16; ++c) h[c] = h0[lane * 16 + c];

    for (int t = 0; t < T; ++t) {
        // hoist this step's x (lanes 0..3) so the load overlaps MACs + reduce
        float xv = 0.f;
        if (lane < 4) xv = X[(size_t)t * HD + row0 + lane];
        // ---- 4 row partial dots (16 MACs each) ----
        float acc[4];
#pragma unroll
        for (int r = 0; r < 4; ++r) {
            float a = 0.f;
#pragma unroll
            for (int c = 0; c < 4; ++c) {
                const float4 wv = w[r][c];
                a += wv.x * h[c * 4 + 0] + wv.y * h[c * 4 + 1] +
                     wv.z * h[c * 4 + 2] + wv.w * h[c * 4 + 3];
            }
            acc[r] = a;
        }
        // ---- butterfly reduce: every lane ends with all 4 full sums ----
#pragma unroll
        for (int r = 0; r < 4; ++r) {
#pragma unroll
            for (int off = 32; off; off >>= 1) acc[r] += __shfl_xor(acc[r], off);
        }
        // ---- lanes 0..3 publish the 4 values in parallel (relaxed, sc1 -> L3) ----
        float* orow = Hout + (size_t)(out0 + t) * HD + row0;
        if (lane < 4) {
            float v = tanhf(xv + acc[lane]);
            __hip_atomic_store(&orow[lane], v, __ATOMIC_RELAXED, __HIP_MEMORY_SCOPE_AGENT);
        }
        if (t + 1 < T) {
            // ---- poll own slice of row t until every dword != SENT ----
            const float* hrow = Hout + (size_t)(out0 + t) * HD + lane * 16;
            int ok;
            do {
                unsigned bad = 0;
#pragma unroll
                for (int c = 0; c < 16; ++c) {
                    h[c] = __hip_atomic_load(&hrow[c], __ATOMIC_RELAXED, __HIP_MEMORY_SCOPE_AGENT);
                    bad |= (unsigned)(__float_as_uint(h[c]) == SENT);
                }
                ok = (bad == 0);
            } while (!__all(ok));
        }
    }
}

// ---------------- row softmax in place ----------------
__global__ __launch_bounds__(256) void softmax_rows(float* __restrict__ S, int N) {
    __shared__ float red[256];
    const int row = blockIdx.x, tid = threadIdx.x;
    float* r = S + (size_t)row * N;
    float lm = -INFINITY;
    for (int i = tid; i < N; i += 256) lm = fmaxf(lm, r[i]);
    red[tid] = lm; __syncthreads();
    for (int o = 128; o; o >>= 1) { if (tid < o) red[tid] = fmaxf(red[tid], red[tid + o]); __syncthreads(); }
    const float M = red[0]; __syncthreads();
    float ls = 0.f;
    for (int i = tid; i < N; i += 256) { float e = expf(r[i] - M); r[i] = e; ls += e; }
    red[tid] = ls; __syncthreads();
    for (int o = 128; o; o >>= 1) { if (tid < o) red[tid] += red[tid + o]; __syncthreads(); }
    const float inv = 1.f / red[0];
    for (int i = tid; i < N; i += 256) r[i] *= inv;
}

// ---------------- online logsumexp over a logits chunk ----------------
__global__ __launch_bounds__(256) void lse_chunk(const float* __restrict__ L, int CN, int c0,
                                                 const int* __restrict__ tgt, float* __restrict__ m,
                                                 float* __restrict__ s, float* __restrict__ tl) {
    __shared__ float red[256];
    const int row = blockIdx.x, tid = threadIdx.x;
    const float* lr = L + (size_t)row * CN;
    float lm = -INFINITY;
    for (int i = tid; i < CN; i += 256) lm = fmaxf(lm, lr[i]);
    red[tid] = lm; __syncthreads();
    for (int o = 128; o; o >>= 1) { if (tid < o) red[tid] = fmaxf(red[tid], red[tid + o]); __syncthreads(); }
    const float M = red[0]; __syncthreads();
    float ls = 0.f;
    for (int i = tid; i < CN; i += 256) ls += expf(lr[i] - M);
    red[tid] = ls; __syncthreads();
    for (int o = 128; o; o >>= 1) { if (tid < o) red[tid] += red[tid + o]; __syncthreads(); }
    if (tid == 0) {
        const float S = red[0];
        const float m0 = m[row];
        const float nm = fmaxf(m0, M);
        const float s0 = s[row];
        const float ns = (m0 == -INFINITY ? 0.f : s0 * expf(m0 - nm)) + S * expf(M - nm);
        m[row] = nm; s[row] = ns;
        const int tg = tgt[row] - c0;
        if (tg >= 0 && tg < CN) tl[row] = lr[tg];
    }
}

// ---------------- final: sum_t (m + log s - tgt_logit) ----------------
__global__ __launch_bounds__(512) void final_loss(const float* __restrict__ m, const float* __restrict__ s,
                                                  const float* __restrict__ tl, float* __restrict__ out) {
    __shared__ float red[512];
    const int tid = threadIdx.x;
    red[tid] = m[tid] + logf(s[tid]) - tl[tid];
    __syncthreads();
    for (int o = 256; o; o >>= 1) { if (tid < o) red[tid] += red[tid + o]; __syncthreads(); }
    if (tid == 0) out[0] = red[0];
}

extern "C" void kernel_launch(void* const* d_in, const int* in_sizes, int n_in,
                              void* d_out, int out_size, void* d_ws, size_t ws_size,
                              hipStream_t stream) {
    const int* src_nums  = (const int*)d_in[0];
    const int* tgt_nums  = (const int*)d_in[1];
    const float* src_emb = (const float*)d_in[2];
    const float* Wx1     = (const float*)d_in[3];
    const float* Wh1     = (const float*)d_in[4];
    const float* b1      = (const float*)d_in[5];
    const float* h01     = (const float*)d_in[6];
    const float* Wx2     = (const float*)d_in[7];
    const float* Wh2     = (const float*)d_in[8];
    const float* b2      = (const float*)d_in[9];
    const float* h02     = (const float*)d_in[10];
    const float* tgt_emb = (const float*)d_in[11];
    const float* dh0     = (const float*)d_in[12];
    const float* dWx     = (const float*)d_in[13];
    const float* dWh     = (const float*)d_in[14];
    const float* db      = (const float*)d_in[15];
    const float* tnhW    = (const float*)d_in[16];
    const float* tnhb    = (const float*)d_in[17];
    const float* outW    = (const float*)d_in[18];
    const float* outb    = (const float*)d_in[19];
    float* out = (float*)d_out;

    float* ws = (float*)d_ws;
    size_t off = 0;
    auto alloc = [&](size_t n) { float* p = ws + off; off += n; return p; };
    float* E     = alloc((size_t)SEQ * HD);
    float* X     = alloc((size_t)SEQ * HD);
    float* H1    = alloc((size_t)SEQ * HD);   // H1, Henc, Hp contiguous: one sentinel fill
    float* Henc  = alloc((size_t)SEQ * HD);
    float* Hp    = alloc((size_t)SEQ * HD);
    float* HencT = alloc((size_t)HD * SEQ);
    float* Satt  = alloc((size_t)SEQ * SEQ);
    float* CH    = alloc((size_t)SEQ * 2 * HD);
    float* Z     = alloc((size_t)SEQ * HD);
    float* Lc    = alloc((size_t)SEQ * NCHUNK);
    float* mrow  = alloc(SEQ);
    float* srow  = alloc(SEQ);
    float* tlrow = alloc(SEQ);

    init_state<<<1, 512, 0, stream>>>(mrow, srow, tlrow);
    fill_sentinel<<<768, 256, 0, stream>>>((float4*)H1, 3 * SEQ * HD / 4);

    // ---- encoder ----
    gather_rows<<<SEQ, 256, 0, stream>>>(src_emb, src_nums, E, HD);
    gemm_nt<<<dim3(HD / 64, SEQ / 64), 256, 0, stream>>>(E, Wx1, b1, X, SEQ, HD, HD, HD, 0);
    scan_rnn3<<<SCAN_WGS, 64, 0, stream>>>(X, Wh1, h01, H1, SEQ, 0);
    gemm_nt<<<dim3(HD / 64, SEQ / 64), 256, 0, stream>>>(H1, Wx2, b2, X, SEQ, HD, HD, HD, 0);
    scan_rnn3<<<SCAN_WGS, 64, 0, stream>>>(X, Wh2, h02, Henc, SEQ, 0);

    // ---- decoder hidden-state scan (pre-step states Hp[0..511]) ----
    gather_rows<<<SEQ, 256, 0, stream>>>(tgt_emb, tgt_nums, E, HD);
    gemm_nt<<<dim3(HD / 64, SEQ / 64), 256, 0, stream>>>(E, dWx, db, X, SEQ, HD, HD, HD, 0);
    scan_rnn3<<<SCAN_WGS, 64, 0, stream>>>(X, dWh, dh0, Hp, SEQ - 1, 1);

    // ---- batched attention ----
    gemm_nt<<<dim3(SEQ / 64, SEQ / 64), 256, 0, stream>>>(Hp, Henc, nullptr, Satt, SEQ, SEQ, HD, SEQ, 0);
    softmax_rows<<<SEQ, 256, 0, stream>>>(Satt, SEQ);
    transpose_k<<<dim3(HD / 32, SEQ / 32), dim3(32, 8), 0, stream>>>(Henc, HencT, SEQ, HD);
    gemm_nt<<<dim3(HD / 64, SEQ / 64), 256, 0, stream>>>(Satt, HencT, nullptr, CH, SEQ, HD, SEQ, 2 * HD, 0);
    copy_right<<<SEQ, 256, 0, stream>>>(Hp, CH);
    gemm_nt<<<dim3(HD / 64, SEQ / 64), 256, 0, stream>>>(CH, tnhW, tnhb, Z, SEQ, HD, 2 * HD, HD, 1);

    // ---- logits + online logsumexp, chunked over vocab ----
    for (int c = 0; c < VOCAB / NCHUNK; ++c) {
        gemm_nt<<<dim3(NCHUNK / 64, SEQ / 64), 256, 0, stream>>>(
            Z, outW + (size_t)c * NCHUNK * HD, outb + (size_t)c * NCHUNK, Lc, SEQ, NCHUNK, HD, NCHUNK, 0);
        lse_chunk<<<SEQ, 256, 0, stream>>>(Lc, NCHUNK, c * NCHUNK, tgt_nums, mrow, srow, tlrow);
    }
    final_loss<<<1, 512, 0, stream>>>(mrow, srow, tlrow, out);
}